// Round 1
// baseline (73.827 us; speedup 1.0000x reference)
//
#include <hip/hip_runtime.h>

#define N2   8192
#define DDIM 256
#define NBLK 64   // 8192/128 column blocks

static constexpr float INV_T = 1.0f / 0.07f;   // 14.2857142857

using bf16x8 = __attribute__((ext_vector_type(8))) __bf16;
using f32x4  = __attribute__((ext_vector_type(4))) float;
using u16x8  = __attribute__((ext_vector_type(8))) unsigned short;
using u16x4  = __attribute__((ext_vector_type(4))) unsigned short;
typedef unsigned short u16;
typedef unsigned int   u32;

// ---------- helpers ----------
__device__ __forceinline__ u16 f2bf(float f) {
    u32 u = __float_as_uint(f);
    u32 r = (u + 0x7fffu + ((u >> 16) & 1u)) >> 16;   // RNE
    return (u16)r;
}
__device__ __forceinline__ float bf2f(u16 b) {
    return __uint_as_float(((u32)b) << 16);
}

// ---------- kernel 1: normalize rows, f32 -> bf16 ----------
__global__ void ntx_norm(const float* __restrict__ z1, const float* __restrict__ z2,
                         u16* __restrict__ zn)
{
    const int w    = threadIdx.x >> 6;
    const int lane = threadIdx.x & 63;
    const int row  = blockIdx.x * 4 + w;

    const float* src = (row < 4096) ? (z1 + (size_t)row * DDIM)
                                    : (z2 + (size_t)(row - 4096) * DDIM);
    float4 v = *(const float4*)(src + lane * 4);
    float ss = v.x * v.x + v.y * v.y + v.z * v.z + v.w * v.w;
    #pragma unroll
    for (int m = 1; m < 64; m <<= 1) ss += __shfl_xor(ss, m, 64);

    float nrm = sqrtf(ss);
    float inv = 1.0f / fmaxf(nrm, 1e-8f);

    u16x4 o;
    o.x = f2bf(v.x * inv); o.y = f2bf(v.y * inv);
    o.z = f2bf(v.z * inv); o.w = f2bf(v.w * inv);
    *(u16x4*)(zn + (size_t)row * DDIM + lane * 4) = o;
}

// ---------- kernel 2: sim = zn@zn^T /T, exp(sim - 1/T), masked diag, row partial sums ----------
// 128x128 tile per block, 4 waves (2x2), BK=64, double-buffered LDS, XOR-swizzled rows.
__global__ __launch_bounds__(256, 2)
void ntx_gemm(const u16* __restrict__ zn, float* __restrict__ partials)
{
    __shared__ u16 lsA[2][128][64];
    __shared__ u16 lsB[2][128][64];

    const int tid  = threadIdx.x;
    const int lane = tid & 63;
    const int w    = tid >> 6;
    const int wr   = w >> 1;
    const int wc   = w & 1;
    const int br   = (int)blockIdx.x / NBLK;
    const int bc   = (int)blockIdx.x % NBLK;

    const int r8  = lane >> 3;         // 0..7 row-in-group
    const int c16 = (lane & 7) * 16;   // logical byte offset within 128B row

    const int fr  = lane & 15;         // fragment row/col
    const int kl  = lane >> 4;         // k-group 0..3
    const int swz = (fr & 7) << 4;     // read-side swizzle

    u16x8 ra[4], rb[4];

    auto gload = [&](int kt) {
        const char* base = (const char*)zn;
        #pragma unroll
        for (int t = 0; t < 4; ++t) {
            const int rl = w * 32 + t * 8 + r8;
            ra[t] = *(const u16x8*)(base + (size_t)(br * 128 + rl) * 512 + kt * 128 + c16);
            rb[t] = *(const u16x8*)(base + (size_t)(bc * 128 + rl) * 512 + kt * 128 + c16);
        }
    };
    auto swrite = [&](int buf) {
        #pragma unroll
        for (int t = 0; t < 4; ++t) {
            const int rl  = w * 32 + t * 8 + r8;
            const int off = c16 ^ ((rl & 7) << 4);   // rl&7 == r8
            *(u16x8*)((char*)&lsA[buf][0][0] + rl * 128 + off) = ra[t];
            *(u16x8*)((char*)&lsB[buf][0][0] + rl * 128 + off) = rb[t];
        }
    };

    f32x4 acc[4][4] = {};

    gload(0);
    swrite(0);
    __syncthreads();

    int buf = 0;
    #pragma unroll
    for (int kt = 0; kt < 4; ++kt) {
        if (kt < 3) gload(kt + 1);       // global loads overlap compute
        #pragma unroll
        for (int ks = 0; ks < 2; ++ks) {
            const int kb = ks * 64 + kl * 16;
            bf16x8 af[4], bv[4];
            #pragma unroll
            for (int mf = 0; mf < 4; ++mf) {
                const int r = wr * 64 + mf * 16 + fr;
                af[mf] = *(const bf16x8*)((const char*)&lsA[buf][0][0] + r * 128 + (kb ^ swz));
            }
            #pragma unroll
            for (int nf = 0; nf < 4; ++nf) {
                const int c = wc * 64 + nf * 16 + fr;
                bv[nf] = *(const bf16x8*)((const char*)&lsB[buf][0][0] + c * 128 + (kb ^ swz));
            }
            #pragma unroll
            for (int mf = 0; mf < 4; ++mf)
                #pragma unroll
                for (int nf = 0; nf < 4; ++nf)
                    acc[mf][nf] = __builtin_amdgcn_mfma_f32_16x16x32_bf16(
                        af[mf], bv[nf], acc[mf][nf], 0, 0, 0);
        }
        if (kt < 3) {
            __syncthreads();     // all waves done reading buf
            swrite(buf ^ 1);
            __syncthreads();     // staged data visible
            buf ^= 1;
        }
    }

    // ---- epilogue: term = exp(sim - 1/T) = exp((dot-1)*INV_T), diag masked; per-row sums ----
    #pragma unroll
    for (int mf = 0; mf < 4; ++mf) {
        float rs0 = 0.f, rs1 = 0.f, rs2 = 0.f, rs3 = 0.f;
        const int rowq = br * 128 + wr * 64 + mf * 16 + kl * 4;   // rows rowq..rowq+3
        const int colb = bc * 128 + wc * 64 + fr;
        #pragma unroll
        for (int nf = 0; nf < 4; ++nf) {
            const int col = colb + nf * 16;
            f32x4 a = acc[mf][nf];
            rs0 += (rowq + 0 == col) ? 0.f : __expf((a[0] - 1.0f) * INV_T);
            rs1 += (rowq + 1 == col) ? 0.f : __expf((a[1] - 1.0f) * INV_T);
            rs2 += (rowq + 2 == col) ? 0.f : __expf((a[2] - 1.0f) * INV_T);
            rs3 += (rowq + 3 == col) ? 0.f : __expf((a[3] - 1.0f) * INV_T);
        }
        #pragma unroll
        for (int m = 1; m < 16; m <<= 1) {
            rs0 += __shfl_xor(rs0, m, 64);
            rs1 += __shfl_xor(rs1, m, 64);
            rs2 += __shfl_xor(rs2, m, 64);
            rs3 += __shfl_xor(rs3, m, 64);
        }
        if (fr == 0) {
            float* p = partials + (size_t)rowq * 128 + bc * 2 + wc;
            p[0]       = rs0;
            p[128]     = rs1;
            p[256]     = rs2;
            p[384]     = rs3;
        }
    }
}

// ---------- kernel 3: per-row loss = ln(S) + 1/T - pos_dot/T ----------
__global__ void ntx_loss(const u16* __restrict__ zn, const float* __restrict__ partials,
                         float* __restrict__ loss)
{
    const int w    = threadIdx.x >> 6;
    const int lane = threadIdx.x & 63;
    const int row  = blockIdx.x * 4 + w;
    const int prow = (row < 4096) ? row + 4096 : row - 4096;

    u16x4 a = *(const u16x4*)(zn + (size_t)row  * DDIM + lane * 4);
    u16x4 b = *(const u16x4*)(zn + (size_t)prow * DDIM + lane * 4);
    float dot = bf2f(a.x) * bf2f(b.x) + bf2f(a.y) * bf2f(b.y)
              + bf2f(a.z) * bf2f(b.z) + bf2f(a.w) * bf2f(b.w);

    float S = partials[(size_t)row * 128 + lane] + partials[(size_t)row * 128 + 64 + lane];

    #pragma unroll
    for (int m = 1; m < 64; m <<= 1) {
        dot += __shfl_xor(dot, m, 64);
        S   += __shfl_xor(S,   m, 64);
    }
    if (lane == 0)
        loss[row] = __logf(S) + INV_T - dot * INV_T;
}

// ---------- kernel 4: deterministic mean ----------
__global__ void ntx_reduce(const float* __restrict__ loss, float* __restrict__ out)
{
    __shared__ float sm[256];
    const int t = threadIdx.x;
    float s = 0.f;
    for (int i = t; i < N2; i += 256) s += loss[i];
    sm[t] = s;
    __syncthreads();
    for (int wdt = 128; wdt > 0; wdt >>= 1) {
        if (t < wdt) sm[t] += sm[t + wdt];
        __syncthreads();
    }
    if (t == 0) out[0] = sm[0] * (1.0f / (float)N2);
}

extern "C" void kernel_launch(void* const* d_in, const int* in_sizes, int n_in,
                              void* d_out, int out_size, void* d_ws, size_t ws_size,
                              hipStream_t stream)
{
    const float* z1 = (const float*)d_in[0];
    const float* z2 = (const float*)d_in[1];
    float* out = (float*)d_out;

    // workspace layout
    u16*   zn       = (u16*)d_ws;                                  // 8192*256*2 = 4 MB
    float* partials = (float*)((char*)d_ws + (size_t)N2 * 512);    // 8192*128*4 = 4 MB
    float* loss     = (float*)((char*)d_ws + 2 * (size_t)N2 * 512);// 32 KB

    ntx_norm  <<<N2 / 4, 256, 0, stream>>>(z1, z2, zn);
    ntx_gemm  <<<NBLK * NBLK, 256, 0, stream>>>(zn, partials);
    ntx_loss  <<<N2 / 4, 256, 0, stream>>>(zn, partials, loss);
    ntx_reduce<<<1, 256, 0, stream>>>(loss, out);
}

// Round 2
// 47.778 us; speedup vs baseline: 1.5452x; 1.5452x over previous
//
#include <hip/hip_runtime.h>

#define N2   8192
#define DDIM 256
#define NBLK 64   // 8192/128 row/col blocks
#define NTRI 2080 // 64*65/2 upper-triangle blocks

static constexpr float INV_T = 1.0f / 0.07f;   // 14.2857142857

using bf16x8 = __attribute__((ext_vector_type(8))) __bf16;
using f32x4  = __attribute__((ext_vector_type(4))) float;
using u16x8  = __attribute__((ext_vector_type(8))) unsigned short;
using u16x4  = __attribute__((ext_vector_type(4))) unsigned short;
typedef unsigned short u16;
typedef unsigned int   u32;

// ---------- helpers ----------
__device__ __forceinline__ u16 f2bf(float f) {
    u32 u = __float_as_uint(f);
    u32 r = (u + 0x7fffu + ((u >> 16) & 1u)) >> 16;   // RNE
    return (u16)r;
}

// ---------- kernel 1: normalize rows, f32 -> bf16 ----------
__global__ void ntx_norm(const float* __restrict__ z1, const float* __restrict__ z2,
                         u16* __restrict__ zn)
{
    const int w    = threadIdx.x >> 6;
    const int lane = threadIdx.x & 63;
    const int row  = blockIdx.x * 4 + w;

    const float* src = (row < 4096) ? (z1 + (size_t)row * DDIM)
                                    : (z2 + (size_t)(row - 4096) * DDIM);
    float4 v = *(const float4*)(src + lane * 4);
    float ss = v.x * v.x + v.y * v.y + v.z * v.z + v.w * v.w;
    #pragma unroll
    for (int m = 1; m < 64; m <<= 1) ss += __shfl_xor(ss, m, 64);

    float nrm = sqrtf(ss);
    float inv = 1.0f / fmaxf(nrm, 1e-8f);

    u16x4 o;
    o.x = f2bf(v.x * inv); o.y = f2bf(v.y * inv);
    o.z = f2bf(v.z * inv); o.w = f2bf(v.w * inv);
    *(u16x4*)(zn + (size_t)row * DDIM + lane * 4) = o;
}

// ---------- kernel 2: upper-triangle sim blocks; exp(sim-1/T); row+col partial sums ----------
// 128x128 tile, 4 waves (2x2), BK=64, SINGLE-buffered LDS (32 KB), XOR-swizzled rows.
__global__ __launch_bounds__(256, 3)
void ntx_gemm(const u16* __restrict__ zn, float* __restrict__ partials,
              float* __restrict__ pos)
{
    __shared__ u16 lsA[128][64];
    __shared__ u16 lsB[128][64];

    const int tid  = threadIdx.x;
    const int lane = tid & 63;
    const int w    = tid >> 6;
    const int wr   = w >> 1;
    const int wc   = w & 1;

    // triangle decode: blockIdx.x -> (br, bc), br <= bc
    const int t = (int)blockIdx.x;
    int br = (int)((129.0f - sqrtf(16641.0f - 8.0f * (float)t)) * 0.5f);
    while ((br + 1) * (129 - (br + 1)) / 2 <= t) ++br;
    while (br * (129 - br) / 2 > t) --br;
    const int bc = br + (t - br * (129 - br) / 2);

    const int r8  = lane >> 3;         // 0..7 row-in-group
    const int c16 = (lane & 7) * 16;   // byte offset within 128B logical row

    const int fr  = lane & 15;         // fragment row/col
    const int kl  = lane >> 4;         // k-group 0..3
    const int swz = (fr & 7) << 4;     // read-side swizzle

    u16x8 ra[4], rb[4];

    auto gload = [&](int kt) {
        const char* base = (const char*)zn;
        #pragma unroll
        for (int tt = 0; tt < 4; ++tt) {
            const int rl = w * 32 + tt * 8 + r8;
            ra[tt] = *(const u16x8*)(base + (size_t)(br * 128 + rl) * 512 + kt * 128 + c16);
            rb[tt] = *(const u16x8*)(base + (size_t)(bc * 128 + rl) * 512 + kt * 128 + c16);
        }
    };
    auto swrite = [&]() {
        #pragma unroll
        for (int tt = 0; tt < 4; ++tt) {
            const int rl  = w * 32 + tt * 8 + r8;
            const int off = c16 ^ ((rl & 7) << 4);   // rl&7 == r8
            *(u16x8*)((char*)&lsA[0][0] + rl * 128 + off) = ra[tt];
            *(u16x8*)((char*)&lsB[0][0] + rl * 128 + off) = rb[tt];
        }
    };

    f32x4 acc[4][4] = {};

    gload(0);
    swrite();
    __syncthreads();

    #pragma unroll
    for (int kt = 0; kt < 4; ++kt) {
        if (kt < 3) gload(kt + 1);       // global prefetch overlaps compute
        #pragma unroll
        for (int ks = 0; ks < 2; ++ks) {
            const int kb = ks * 64 + kl * 16;
            bf16x8 af[4], bv[4];
            #pragma unroll
            for (int mf = 0; mf < 4; ++mf) {
                const int r = wr * 64 + mf * 16 + fr;
                af[mf] = *(const bf16x8*)((const char*)&lsA[0][0] + r * 128 + (kb ^ swz));
            }
            #pragma unroll
            for (int nf = 0; nf < 4; ++nf) {
                const int c = wc * 64 + nf * 16 + fr;
                bv[nf] = *(const bf16x8*)((const char*)&lsB[0][0] + c * 128 + (kb ^ swz));
            }
            #pragma unroll
            for (int mf = 0; mf < 4; ++mf)
                #pragma unroll
                for (int nf = 0; nf < 4; ++nf)
                    acc[mf][nf] = __builtin_amdgcn_mfma_f32_16x16x32_bf16(
                        af[mf], bv[nf], acc[mf][nf], 0, 0, 0);
        }
        if (kt < 3) {
            __syncthreads();     // all waves done reading LDS
            swrite();
            __syncthreads();     // staged data visible
        }
    }

    // ---- epilogue ----
    // e = exp((dot-1)/T), diag masked. Row sums -> partials[row][2*bc+wc].
    // Off-diagonal blocks additionally contribute transpose col sums ->
    // partials[col][2*br+wr]. Slot sets are disjoint and tile [0,128).
    const bool offdiag = (br != bc);
    const bool posblk  = (bc == br + 32);
    float colsum[4] = {0.f, 0.f, 0.f, 0.f};

    #pragma unroll
    for (int mf = 0; mf < 4; ++mf) {
        float rs[4] = {0.f, 0.f, 0.f, 0.f};
        const int rowq = br * 128 + wr * 64 + mf * 16 + kl * 4;
        #pragma unroll
        for (int nf = 0; nf < 4; ++nf) {
            const int col = bc * 128 + wc * 64 + nf * 16 + fr;
            f32x4 a = acc[mf][nf];
            #pragma unroll
            for (int j = 0; j < 4; ++j) {
                float e = (rowq + j == col) ? 0.f : __expf((a[j] - 1.0f) * INV_T);
                rs[j]       += e;
                colsum[nf]  += e;
                if (posblk && (rowq + j + 4096 == col)) {
                    pos[rowq + j] = a[j];
                    pos[col]      = a[j];
                }
            }
        }
        #pragma unroll
        for (int m = 1; m < 16; m <<= 1) {
            #pragma unroll
            for (int j = 0; j < 4; ++j) rs[j] += __shfl_xor(rs[j], m, 64);
        }
        if (fr == 0) {
            float* p = partials + (size_t)rowq * 128 + bc * 2 + wc;
            p[0]   = rs[0];
            p[128] = rs[1];
            p[256] = rs[2];
            p[384] = rs[3];
        }
    }

    if (offdiag) {
        #pragma unroll
        for (int m = 16; m < 64; m <<= 1) {
            #pragma unroll
            for (int nf = 0; nf < 4; ++nf) colsum[nf] += __shfl_xor(colsum[nf], m, 64);
        }
        if (kl == 0) {
            #pragma unroll
            for (int nf = 0; nf < 4; ++nf) {
                const int col = bc * 128 + wc * 64 + nf * 16 + fr;
                partials[(size_t)col * 128 + br * 2 + wr] = colsum[nf];
            }
        }
    }
}

// ---------- kernel 3: per-row loss = ln(S) + 1/T - pos_dot/T ----------
__global__ void ntx_loss(const float* __restrict__ partials, const float* __restrict__ pos,
                         float* __restrict__ loss)
{
    const int w    = threadIdx.x >> 6;
    const int lane = threadIdx.x & 63;
    const int row  = blockIdx.x * 4 + w;

    float S = partials[(size_t)row * 128 + lane] + partials[(size_t)row * 128 + 64 + lane];
    #pragma unroll
    for (int m = 1; m < 64; m <<= 1) S += __shfl_xor(S, m, 64);

    if (lane == 0)
        loss[row] = __logf(S) + INV_T - pos[row] * INV_T;
}

// ---------- kernel 4: deterministic mean ----------
__global__ void ntx_reduce(const float* __restrict__ loss, float* __restrict__ out)
{
    __shared__ float sm[1024];
    const int t = threadIdx.x;
    float s = 0.f;
    for (int i = t; i < N2; i += 1024) s += loss[i];
    sm[t] = s;
    __syncthreads();
    for (int wdt = 512; wdt > 0; wdt >>= 1) {
        if (t < wdt) sm[t] += sm[t + wdt];
        __syncthreads();
    }
    if (t == 0) out[0] = sm[0] * (1.0f / (float)N2);
}

extern "C" void kernel_launch(void* const* d_in, const int* in_sizes, int n_in,
                              void* d_out, int out_size, void* d_ws, size_t ws_size,
                              hipStream_t stream)
{
    const float* z1 = (const float*)d_in[0];
    const float* z2 = (const float*)d_in[1];
    float* out = (float*)d_out;

    // workspace layout
    u16*   zn       = (u16*)d_ws;                                   // 8192*256*2 = 4 MB
    float* partials = (float*)((char*)d_ws + (size_t)N2 * 512);     // 8192*128*4 = 4 MB
    float* loss     = (float*)((char*)d_ws + 2 * (size_t)N2 * 512); // 32 KB
    float* pos      = loss + N2;                                    // 32 KB

    ntx_norm  <<<N2 / 4, 256, 0, stream>>>(z1, z2, zn);
    ntx_gemm  <<<NTRI, 256, 0, stream>>>(zn, partials, pos);
    ntx_loss  <<<N2 / 4, 256, 0, stream>>>(partials, pos, loss);
    ntx_reduce<<<1, 1024, 0, stream>>>(loss, out);
}